// Round 5
// baseline (152.044 us; speedup 1.0000x reference)
//
#include <hip/hip_runtime.h>
#include <cstdint>
#include <cstddef>

// MMD loss, N=8192 (b=4096), D=512.
//   bw closed form: sum(L2) = 2n*S - 2*||colsum||^2
//   R5: k_mmd is now LDS-FREE: int8 fragments are 16B K-contiguous chunks of
//       global rows, and the whole Ti8 matrix is 4MB = L2-resident per XCD.
//       Fragments load straight from global->L2 into VGPRs. No staging, no
//       barriers (the 8-barrier lockstep was ~60% of k_mmd's runtime; no pipe
//       was saturated). New bound: L2 read volume 532MB @ 34.5TB/s ~ 15us.
//   R4: INT8 MFMA 16x16x64 (scale 1/16, exact int32 acc), diag forced exact.
//   Epilogue: sum_k exp(-L2/(bw*2^k)) = e+e^2+e^4+e^8+e^16, e=exp2(-L2*log2e/(16bw))
//   R2: no single-address atomics (were 107us of serialization).

#define D_DIM 512
#define B_ROWS 4096
#define N_ROWS 8192
#define NTILES 64        // 8192 / 128
#define NBLK_MMD 2080    // 64*65/2

typedef __attribute__((ext_vector_type(4))) int i32x4;

__device__ inline float waveReduce(float v) {
    #pragma unroll
    for (int off = 32; off > 0; off >>= 1) v += __shfl_down(v, off, 64);
    return v;
}

__device__ inline int q8(float x) {
    int v = (int)rintf(x * 16.f);             // RNE; s = 1/16
    v = v > 127 ? 127 : v;
    v = v < -127 ? -127 : v;
    return v & 255;
}

// ---- K1: per-row sq norms (fp32, exact) + fp32->int8 quantize ----
__global__ __launch_bounds__(256) void k_rowstats(const float* __restrict__ src,
                                                  const float* __restrict__ tgt,
                                                  unsigned char* __restrict__ Ti8,
                                                  float* __restrict__ sq) {
    int wave = threadIdx.x >> 6;
    int lane = threadIdx.x & 63;
    int row  = blockIdx.x * 4 + wave;
    const float* base = (row < B_ROWS) ? (src + (size_t)row * D_DIM)
                                       : (tgt + (size_t)(row - B_ROWS) * D_DIM);
    float4 a = ((const float4*)base)[lane * 2];
    float4 b = ((const float4*)base)[lane * 2 + 1];
    uint2 o;
    o.x = (unsigned)(q8(a.x) | (q8(a.y) << 8) | (q8(a.z) << 16) | (q8(a.w) << 24));
    o.y = (unsigned)(q8(b.x) | (q8(b.y) << 8) | (q8(b.z) << 16) | (q8(b.w) << 24));
    ((uint2*)(Ti8 + (size_t)row * D_DIM))[lane] = o;
    float s = a.x*a.x + a.y*a.y + a.z*a.z + a.w*a.w
            + b.x*b.x + b.y*b.y + b.z*b.z + b.w*b.w;
    s = waveReduce(s);
    if (lane == 0) sq[row] = s;
}

// ---- K2: exact int8 column-sum partials (64 blocks x 128 rows) ----
__global__ __launch_bounds__(256) void k_colsum(const unsigned int* __restrict__ Tu,
                                                int* __restrict__ partial) {
    int t    = threadIdx.x;
    int ci   = t & 127;            // uint index within a 512-B row
    int half = t >> 7;             // 0/1: interleaved rows
    int r0   = blockIdx.x * 128 + half;
    int a0 = 0, a1 = 0, a2 = 0, a3 = 0;
    #pragma unroll 4
    for (int j = 0; j < 64; ++j) {
        unsigned int u = Tu[(size_t)(r0 + 2 * j) * 128 + ci];
        a0 += (int)(signed char)(u);
        a1 += (int)(signed char)(u >> 8);
        a2 += (int)(signed char)(u >> 16);
        a3 += (int)(signed char)(u >> 24);
    }
    int base = ((blockIdx.x * 2 + half) * 512) + ci * 4;
    partial[base + 0] = a0;
    partial[base + 1] = a1;
    partial[base + 2] = a2;
    partial[base + 3] = a3;
}

// ---- K3: finalize bandwidth -> c16 = -log2(e)/(16*bw) ----
__global__ __launch_bounds__(512) void k_bw(const int* __restrict__ partial,
                                            const float* __restrict__ sq,
                                            float* __restrict__ c16out) {
    int t = threadIdx.x;
    int csum = 0;
    #pragma unroll 8
    for (int i = 0; i < 128; ++i) csum += partial[i * 512 + t];
    float cs = (float)csum * 0.0625f;          // * s (1/16)
    float p = cs * cs;
    float ssq = 0.f;
    #pragma unroll
    for (int i = 0; i < 16; ++i) ssq += sq[t + i * 512];
    __shared__ float r8[8], q8s[8];
    float wp = waveReduce(p);
    float wq = waveReduce(ssq);
    if ((t & 63) == 0) { r8[t >> 6] = wp; q8s[t >> 6] = wq; }
    __syncthreads();
    if (t == 0) {
        double P = 0.0, Q = 0.0;
        #pragma unroll
        for (int i = 0; i < 8; ++i) { P += r8[i]; Q += q8s[i]; }
        double n = (double)N_ROWS;
        double sumL2 = 2.0 * n * Q - 2.0 * P;
        double bw = sumL2 / (n * n - n) / 4.0;   // / KERNEL_MUL^(NUM/2)
        c16out[0] = (float)(-1.4426950408889634 / (16.0 * bw));
    }
}

// ---- K4: LDS-free int8 Gram + fused MMD epilogue (fragments direct from L2) ----
__global__ __launch_bounds__(256) void k_mmd(const unsigned char* __restrict__ Ti8,
                                             const float* __restrict__ sq,
                                             const float* __restrict__ c16in,
                                             float* __restrict__ blockpart) {
    int rem = blockIdx.x;
    int ti = 0, rowlen = NTILES;
    while (rem >= rowlen) { rem -= rowlen; rowlen--; ti++; }
    int tj = ti + rem;

    int tid  = threadIdx.x;
    int wave = tid >> 6;
    int lane = tid & 63;
    int waveM = (wave >> 1) * 64;
    int waveN = (wave & 1) * 64;
    int l15   = lane & 15;
    int quad  = lane >> 4;

    float c16 = c16in[0];                    // -log2e/(16 bw)
    float cgq = -2.f * c16 * (1.f / 256.f);  // fold s^2 = 1/256

    // per-lane row base pointers, viewed as arrays of 16B chunks (32 per row)
    const i32x4* arow[4];
    const i32x4* brow[4];
    #pragma unroll
    for (int mi = 0; mi < 4; ++mi)
        arow[mi] = (const i32x4*)(Ti8 + ((size_t)ti * 128 + waveM + mi * 16 + l15) * D_DIM);
    #pragma unroll
    for (int ni = 0; ni < 4; ++ni)
        brow[ni] = (const i32x4*)(Ti8 + ((size_t)tj * 128 + waveN + ni * 16 + l15) * D_DIM);

    i32x4 acc[4][4];
    #pragma unroll
    for (int mi = 0; mi < 4; ++mi)
        #pragma unroll
        for (int ni = 0; ni < 4; ++ni)
            acc[mi][ni] = (i32x4){0, 0, 0, 0};

    // K=512 as 8 MFMA steps of K=64; lane's fragment = chunk (kk*4 + quad).
    #pragma unroll
    for (int kk = 0; kk < 8; ++kk) {
        int c = kk * 4 + quad;
        i32x4 af[4], bf[4];
        #pragma unroll
        for (int mi = 0; mi < 4; ++mi) af[mi] = arow[mi][c];
        #pragma unroll
        for (int ni = 0; ni < 4; ++ni) bf[ni] = brow[ni][c];
        #pragma unroll
        for (int mi = 0; mi < 4; ++mi)
            #pragma unroll
            for (int ni = 0; ni < 4; ++ni)
                acc[mi][ni] = __builtin_amdgcn_mfma_i32_16x16x64_i8(
                    af[mi], bf[ni], acc[mi][ni], 0, 0, 0);
    }

    // epilogue: sq loads direct from global (tiny, L2-hot), pre-scaled
    const float* sqA = sq + ti * 128;
    const float* sqB = sq + tj * 128;
    float trow16[16];
    #pragma unroll
    for (int mi = 0; mi < 4; ++mi)
        #pragma unroll
        for (int r = 0; r < 4; ++r)
            trow16[mi * 4 + r] = sqA[waveM + mi * 16 + quad * 4 + r] * c16;
    float tcol16[4];
    #pragma unroll
    for (int ni = 0; ni < 4; ++ni)
        tcol16[ni] = sqB[waveN + ni * 16 + l15] * c16;

    bool dtile = (ti == tj);
    float psum = 0.f;
    #pragma unroll
    for (int mi = 0; mi < 4; ++mi) {
        #pragma unroll
        for (int ni = 0; ni < 4; ++ni) {
            #pragma unroll
            for (int r = 0; r < 4; ++r) {
                float g   = (float)acc[mi][ni][r];   // exact: |G| < 2^24
                float t16 = __builtin_fmaf(g, cgq, trow16[mi * 4 + r]) + tcol16[ni];
                float e1  = __builtin_amdgcn_exp2f(t16);
                float e2  = e1 * e1;
                float e4  = e2 * e2;
                float e8  = e4 * e4;
                float e16 = e8 * e8;
                float ks5 = ((e1 + e2) + (e4 + e8)) + e16;
                int rl = waveM + mi * 16 + quad * 4 + r;
                int cl = waveN + ni * 16 + l15;
                psum += (dtile && rl == cl) ? 5.0f : ks5;   // exact diagonal
            }
        }
    }

    __shared__ float red[4];
    float w = waveReduce(psum);
    if (lane == 0) red[wave] = w;
    __syncthreads();
    if (tid == 0) {
        float tot   = red[0] + red[1] + red[2] + red[3];
        float sign  = ((ti < 32) == (tj < 32)) ? 1.f : -1.f;
        float scale = (ti == tj) ? sign : 2.f * sign;
        blockpart[blockIdx.x] = tot * scale;   // no atomic
    }
}

// ---- K5: reduce block partials -> final scalar ----
__global__ __launch_bounds__(256) void k_final(const float* __restrict__ bp,
                                               float* __restrict__ out) {
    int t = threadIdx.x;
    float s = 0.f;
    for (int i = t; i < NBLK_MMD; i += 256) s += bp[i];
    __shared__ float r4[4];
    float w = waveReduce(s);
    if ((t & 63) == 0) r4[t >> 6] = w;
    __syncthreads();
    if (t == 0)
        out[0] = (r4[0] + r4[1] + r4[2] + r4[3]) * (1.f / (4096.f * 4096.f));
}

extern "C" void kernel_launch(void* const* d_in, const int* in_sizes, int n_in,
                              void* d_out, int out_size, void* d_ws, size_t ws_size,
                              hipStream_t stream) {
    const float* src = (const float*)d_in[0];
    const float* tgt = (const float*)d_in[1];

    uint8_t* ws = (uint8_t*)d_ws;
    unsigned char* Ti8 = (unsigned char*)ws;                   // 4,194,304 B
    size_t off = 4194304;
    float* sq      = (float*)(ws + off); off += 32768;         // 8192 f
    int*   partial = (int*)  (ws + off); off += 128 * 512 * 4; // 256 KB
    float* bp      = (float*)(ws + off); off += 8320;
    float* c16     = (float*)(ws + off);

    k_rowstats<<<2048, 256, 0, stream>>>(src, tgt, Ti8, sq);
    k_colsum  <<<64, 256, 0, stream>>>((const unsigned int*)Ti8, partial);
    k_bw      <<<1, 512, 0, stream>>>(partial, sq, c16);
    k_mmd     <<<NBLK_MMD, 256, 0, stream>>>(Ti8, sq, c16, bp);
    k_final   <<<1, 256, 0, stream>>>(bp, (float*)d_out);
}

// Round 6
// 110.913 us; speedup vs baseline: 1.3708x; 1.3708x over previous
//
#include <hip/hip_runtime.h>
#include <cstdint>
#include <cstddef>

// MMD loss, N=8192 (b=4096), D=512.
//   bw closed form: sum(L2) = 2n*S - 2*||colsum||^2
//   R6: FRAGMENT-MAJOR int8 layout. R5's LDS-free k_mmd was right but its
//       row-major layout made every fragment load 16-way segmented (16 rows
//       x 64B) -> 77us. Now chunk (rb,c) [16 rows x 16B] is stored as one
//       contiguous 256B block; a wave's fragment load = one coalesced 1KB
//       transaction. Zero barriers, zero LDS in k_mmd; Ti8 (4MB) is
//       L2-resident. Bound: 532MB L2 reads @ ~30TB/s ~ 18us.
//   R4: INT8 MFMA 16x16x64 (scale 1/16, exact int32 acc), diag forced exact.
//   Epilogue: sum_k exp(-L2/(bw*2^k)) = e+e^2+e^4+e^8+e^16, e=exp2(-L2*log2e/(16bw))
//   R2: no single-address atomics (were 107us of serialization).

#define D_DIM 512
#define B_ROWS 4096
#define N_ROWS 8192
#define NTILES 64        // 8192 / 128
#define NBLK_MMD 2080    // 64*65/2

typedef __attribute__((ext_vector_type(4))) int i32x4;

__device__ inline float waveReduce(float v) {
    #pragma unroll
    for (int off = 32; off > 0; off >>= 1) v += __shfl_down(v, off, 64);
    return v;
}

__device__ inline int q8(float x) {
    int v = (int)rintf(x * 16.f);             // RNE; s = 1/16
    v = v > 127 ? 127 : v;
    v = v < -127 ? -127 : v;
    return v & 255;
}

// Fragment-major address: row r, 16B-chunk c (0..31):
//   rb = r>>4, w = r&15;  byte addr = ((rb*32 + c) << 8) + w*16

// ---- K1: per-row sq norms (fp32, exact) + fp32->int8 quantize (frag-major) ----
__global__ __launch_bounds__(256) void k_rowstats(const float* __restrict__ src,
                                                  const float* __restrict__ tgt,
                                                  unsigned char* __restrict__ Tp,
                                                  float* __restrict__ sq) {
    int wave = threadIdx.x >> 6;
    int lane = threadIdx.x & 63;
    int row  = blockIdx.x * 4 + wave;
    const float* base = (row < B_ROWS) ? (src + (size_t)row * D_DIM)
                                       : (tgt + (size_t)(row - B_ROWS) * D_DIM);
    float4 a = ((const float4*)base)[lane * 2];
    float4 b = ((const float4*)base)[lane * 2 + 1];
    uint2 o;   // bytes [8*lane, 8*lane+8) of the quantized row
    o.x = (unsigned)(q8(a.x) | (q8(a.y) << 8) | (q8(a.z) << 16) | (q8(a.w) << 24));
    o.y = (unsigned)(q8(b.x) | (q8(b.y) << 8) | (q8(b.z) << 16) | (q8(b.w) << 24));
    int rb = row >> 4, w = row & 15;
    int c  = lane >> 1, h = lane & 1;
    *(uint2*)(Tp + (((size_t)(rb * 32 + c)) << 8) + w * 16 + h * 8) = o;
    float s = a.x*a.x + a.y*a.y + a.z*a.z + a.w*a.w
            + b.x*b.x + b.y*b.y + b.z*b.z + b.w*b.w;
    s = waveReduce(s);
    if (lane == 0) sq[row] = s;
}

// ---- K2: exact int8 column-sum partials from frag-major layout ----
// P = ||colsum||^2 is permutation-invariant over columns, so any consistent
// column ordering works. Thread t: uint-col u = t&127 (c=u>>2,q=u&3),
// w-half = t>>7. 64 blocks x 8 row-blocks each -> 128 partial rows.
__global__ __launch_bounds__(256) void k_colsum(const unsigned int* __restrict__ Tu,
                                                int* __restrict__ partial) {
    int t   = threadIdx.x;
    int u   = t & 127;
    int c   = u >> 2, q = u & 3;
    int sub = t >> 7;              // w in [sub*8, sub*8+8)
    int a0 = 0, a1 = 0, a2 = 0, a3 = 0;
    #pragma unroll 2
    for (int j = 0; j < 8; ++j) {
        int rb = blockIdx.x * 8 + j;
        #pragma unroll
        for (int wv = 0; wv < 8; ++wv) {
            int w = sub * 8 + wv;
            unsigned int v = Tu[(size_t)(rb * 32 + c) * 64 + w * 4 + q];
            a0 += (int)(signed char)(v);
            a1 += (int)(signed char)(v >> 8);
            a2 += (int)(signed char)(v >> 16);
            a3 += (int)(signed char)(v >> 24);
        }
    }
    int basep = (blockIdx.x * 2 + sub) * 512 + u * 4;
    partial[basep + 0] = a0;
    partial[basep + 1] = a1;
    partial[basep + 2] = a2;
    partial[basep + 3] = a3;
}

// ---- K3: finalize bandwidth -> c16 = -log2(e)/(16*bw) ----
__global__ __launch_bounds__(512) void k_bw(const int* __restrict__ partial,
                                            const float* __restrict__ sq,
                                            float* __restrict__ c16out) {
    int t = threadIdx.x;
    int csum = 0;
    #pragma unroll 8
    for (int i = 0; i < 128; ++i) csum += partial[i * 512 + t];
    float cs = (float)csum * 0.0625f;          // * s (1/16)
    float p = cs * cs;
    float ssq = 0.f;
    #pragma unroll
    for (int i = 0; i < 16; ++i) ssq += sq[t + i * 512];
    __shared__ float r8[8], q8s[8];
    float wp = waveReduce(p);
    float wq = waveReduce(ssq);
    if ((t & 63) == 0) { r8[t >> 6] = wp; q8s[t >> 6] = wq; }
    __syncthreads();
    if (t == 0) {
        double P = 0.0, Q = 0.0;
        #pragma unroll
        for (int i = 0; i < 8; ++i) { P += r8[i]; Q += q8s[i]; }
        double n = (double)N_ROWS;
        double sumL2 = 2.0 * n * Q - 2.0 * P;
        double bw = sumL2 / (n * n - n) / 4.0;   // / KERNEL_MUL^(NUM/2)
        c16out[0] = (float)(-1.4426950408889634 / (16.0 * bw));
    }
}

// ---- K4: LDS-free, barrier-free int8 Gram + fused MMD epilogue ----
__global__ __launch_bounds__(256) void k_mmd(const unsigned char* __restrict__ Tp,
                                             const float* __restrict__ sq,
                                             const float* __restrict__ c16in,
                                             float* __restrict__ blockpart) {
    int rem = blockIdx.x;
    int ti = 0, rowlen = NTILES;
    while (rem >= rowlen) { rem -= rowlen; rowlen--; ti++; }
    int tj = ti + rem;

    int tid  = threadIdx.x;
    int wave = tid >> 6;
    int lane = tid & 63;
    int waveM = (wave >> 1) * 64;
    int waveN = (wave & 1) * 64;
    int l15   = lane & 15;
    int quad  = lane >> 4;

    float c16 = c16in[0];                    // -log2e/(16 bw)
    float cgq = -2.f * c16 * (1.f / 256.f);  // fold s^2 = 1/256

    // row-block bases: A rows = ti*128 + waveM + mi*16 + l15
    //   rbA = ti*8 + (wave>>1)*4 + mi ; frag at ((rb*32 + c)<<8) + l15*16
    int rbA = ti * 8 + (wave >> 1) * 4;
    int rbB = tj * 8 + (wave & 1) * 4;

    i32x4 acc[4][4];
    #pragma unroll
    for (int mi = 0; mi < 4; ++mi)
        #pragma unroll
        for (int ni = 0; ni < 4; ++ni)
            acc[mi][ni] = (i32x4){0, 0, 0, 0};

    // K=512 as 8 MFMA steps of K=64; chunk c = kk*4 + quad.
    // Each fragment load = one contiguous 1KB wave transaction.
    #pragma unroll
    for (int kk = 0; kk < 8; ++kk) {
        int coff = (kk * 4 + quad) * 256 + l15 * 16;
        i32x4 af[4], bf[4];
        #pragma unroll
        for (int mi = 0; mi < 4; ++mi)
            af[mi] = *(const i32x4*)(Tp + (((size_t)(rbA + mi)) << 13) + coff);
        #pragma unroll
        for (int ni = 0; ni < 4; ++ni)
            bf[ni] = *(const i32x4*)(Tp + (((size_t)(rbB + ni)) << 13) + coff);
        #pragma unroll
        for (int mi = 0; mi < 4; ++mi)
            #pragma unroll
            for (int ni = 0; ni < 4; ++ni)
                acc[mi][ni] = __builtin_amdgcn_mfma_i32_16x16x64_i8(
                    af[mi], bf[ni], acc[mi][ni], 0, 0, 0);
    }

    // epilogue: sq loads direct from global (tiny, L2-hot), pre-scaled
    const float* sqA = sq + ti * 128;
    const float* sqB = sq + tj * 128;
    float trow16[16];
    #pragma unroll
    for (int mi = 0; mi < 4; ++mi)
        #pragma unroll
        for (int r = 0; r < 4; ++r)
            trow16[mi * 4 + r] = sqA[waveM + mi * 16 + quad * 4 + r] * c16;
    float tcol16[4];
    #pragma unroll
    for (int ni = 0; ni < 4; ++ni)
        tcol16[ni] = sqB[waveN + ni * 16 + l15] * c16;

    bool dtile = (ti == tj);
    float psum = 0.f;
    #pragma unroll
    for (int mi = 0; mi < 4; ++mi) {
        #pragma unroll
        for (int ni = 0; ni < 4; ++ni) {
            #pragma unroll
            for (int r = 0; r < 4; ++r) {
                float g   = (float)acc[mi][ni][r];   // exact: |G| < 2^24
                float t16 = __builtin_fmaf(g, cgq, trow16[mi * 4 + r]) + tcol16[ni];
                float e1  = __builtin_amdgcn_exp2f(t16);
                float e2  = e1 * e1;
                float e4  = e2 * e2;
                float e8  = e4 * e4;
                float e16 = e8 * e8;
                float ks5 = ((e1 + e2) + (e4 + e8)) + e16;
                int rl = waveM + mi * 16 + quad * 4 + r;
                int cl = waveN + ni * 16 + l15;
                psum += (dtile && rl == cl) ? 5.0f : ks5;   // exact diagonal
            }
        }
    }

    __shared__ float red[4];
    float w = waveReduce(psum);
    if (lane == 0) red[wave] = w;
    __syncthreads();
    if (tid == 0) {
        float tot   = red[0] + red[1] + red[2] + red[3];
        float sign  = ((ti < 32) == (tj < 32)) ? 1.f : -1.f;
        float scale = (ti == tj) ? sign : 2.f * sign;
        blockpart[blockIdx.x] = tot * scale;   // no atomic
    }
}

// ---- K5: reduce block partials -> final scalar ----
__global__ __launch_bounds__(256) void k_final(const float* __restrict__ bp,
                                               float* __restrict__ out) {
    int t = threadIdx.x;
    float s = 0.f;
    for (int i = t; i < NBLK_MMD; i += 256) s += bp[i];
    __shared__ float r4[4];
    float w = waveReduce(s);
    if ((t & 63) == 0) r4[t >> 6] = w;
    __syncthreads();
    if (t == 0)
        out[0] = (r4[0] + r4[1] + r4[2] + r4[3]) * (1.f / (4096.f * 4096.f));
}

extern "C" void kernel_launch(void* const* d_in, const int* in_sizes, int n_in,
                              void* d_out, int out_size, void* d_ws, size_t ws_size,
                              hipStream_t stream) {
    const float* src = (const float*)d_in[0];
    const float* tgt = (const float*)d_in[1];

    uint8_t* ws = (uint8_t*)d_ws;
    unsigned char* Tp = (unsigned char*)ws;                    // 4,194,304 B
    size_t off = 4194304;
    float* sq      = (float*)(ws + off); off += 32768;         // 8192 f
    int*   partial = (int*)  (ws + off); off += 128 * 512 * 4; // 256 KB
    float* bp      = (float*)(ws + off); off += 8320;
    float* c16     = (float*)(ws + off);

    k_rowstats<<<2048, 256, 0, stream>>>(src, tgt, Tp, sq);
    k_colsum  <<<64, 256, 0, stream>>>((const unsigned int*)Tp, partial);
    k_bw      <<<1, 512, 0, stream>>>(partial, sq, c16);
    k_mmd     <<<NBLK_MMD, 256, 0, stream>>>(Tp, sq, c16, bp);
    k_final   <<<1, 256, 0, stream>>>(bp, (float*)d_out);
}